// Round 20
// baseline (167.128 us; speedup 1.0000x reference)
//
#include <hip/hip_runtime.h>

typedef unsigned short u16;
typedef unsigned int   u32;
typedef unsigned char  u8;

using bf16x8 = __attribute__((ext_vector_type(8))) __bf16;
using f32x4  = __attribute__((ext_vector_type(4))) float;

__device__ __forceinline__ u16 f2bf(float f) {
    u32 u = __float_as_uint(f);
    return (u16)((u + 0x7FFFu + ((u >> 16) & 1u)) >> 16);
}

#define MFMA(a, b, c) __builtin_amdgcn_mfma_f32_16x16x32_bf16((a), (b), (c), 0, 0, 0)
#define EXP2(x) __builtin_amdgcn_exp2f(x)

// async global->LDS 16B: per-lane global source, wave-uniform LDS base + lane*16
__device__ __forceinline__ void gll16(const u16* g, u16* l) {
    __builtin_amdgcn_global_load_lds(
        (const __attribute__((address_space(1))) void*)g,
        (__attribute__((address_space(3))) void*)l, 16, 0, 0);
}

// ---------------------------------------------------------------------------
// MERGED prep: fp32->bf16 conversion of hs/ehs (blocks 0..3839) + 4 weight
// transposes Wt[n][k] = bf16(W[k][n]) (blocks 3840..10239). (R19-proven.)
// ---------------------------------------------------------------------------
__global__ __launch_bounds__(256) void prep_kernel(
    const float* __restrict__ hs, u16* __restrict__ hbuf,
    const float* __restrict__ ehs, u16* __restrict__ ebuf,
    const float* __restrict__ W0, const float* __restrict__ W1,
    const float* __restrict__ W2, const float* __restrict__ W3,
    u16* __restrict__ T0, u16* __restrict__ T1,
    u16* __restrict__ T2, u16* __restrict__ T3) {
    const int bid = blockIdx.x;
    const int tid = threadIdx.x;
    if (bid < 3840) {
        const float* in = (bid < 1280) ? hs : ehs;
        u16* out = (bid < 1280) ? hbuf : ebuf;
        const int i = ((bid < 1280) ? bid : bid - 1280) * 256 + tid;
        const float4 a = ((const float4*)in)[i * 2];
        const float4 b = ((const float4*)in)[i * 2 + 1];
        union { uint4 u; u16 s[8]; } cv;
        cv.s[0] = f2bf(a.x); cv.s[1] = f2bf(a.y);
        cv.s[2] = f2bf(a.z); cv.s[3] = f2bf(a.w);
        cv.s[4] = f2bf(b.x); cv.s[5] = f2bf(b.y);
        cv.s[6] = f2bf(b.z); cv.s[7] = f2bf(b.w);
        ((uint4*)out)[i] = cv.u;
    } else {
        const int N = 1280;
        const int t = bid - 3840;        // 0..6399
        const int z = t / 1600;
        const int r = t % 1600;
        const float* W = (z == 0) ? W0 : (z == 1) ? W1 : (z == 2) ? W2 : W3;
        u16* T = (z == 0) ? T0 : (z == 1) ? T1 : (z == 2) ? T2 : T3;
        __shared__ float tt[32][33];
        const int bx = (r % 40) * 32, by = (r / 40) * 32;
        const int x = tid & 31, ty = tid >> 5;
#pragma unroll
        for (int j = 0; j < 4; j++) {
            const int y = ty + j * 8;
            tt[y][x] = W[(size_t)(by + y) * N + (bx + x)];
        }
        __syncthreads();
#pragma unroll
        for (int j = 0; j < 4; j++) {
            const int y = ty + j * 8;
            T[(size_t)(bx + y) * N + (by + x)] = f2bf(tt[x][y]);
        }
    }
}

// ---------------------------------------------------------------------------
// C[M,N] = A[M,K] @ Bt[N,K]^T, bf16 in. m97-structure, 64x64 TILE:
// BM = MI*32, BN = NI*32 (MI=NI=2 -> 32 KB LDS -> 5 blocks/CU; K/V grids
// 1280 blocks double the latency-absorbing overlap vs R19's 2.5 blk/CU).
// global_load_lds staging (4 loads/thread), pre-swizzled source chunk
// (^= row&7), swizzled ds_read_b128, double-buffer, vmcnt(0)+barrier/K-tile.
// Wave w: rows [ (w>>1)*MI*16 ), cols [ (w&1)*NI*16 ).
// ---------------------------------------------------------------------------
template <int MI, int NI, bool TRANSC, bool EPI>
__global__ __launch_bounds__(256) void gemm2_kernel(
    const u16* __restrict__ A, const u16* __restrict__ Bt, void* __restrict__ Cp,
    const float* __restrict__ bias, const float* __restrict__ resid,
    const int M, const int N, const int K) {
    __shared__ __align__(16) u16 Al[2][MI * 32 * 64];
    __shared__ __align__(16) u16 Bl[2][NI * 32 * 64];
    const int tid = threadIdx.x;
    const int lane = tid & 63, w = tid >> 6;
    const int wr = w >> 1, wc = w & 1;
    const int lr = lane & 15, lq = lane >> 4;
    const int m0 = blockIdx.y * (MI * 32), n0 = blockIdx.x * (NI * 32);

    const int f_r = tid >> 3;                       // row within 32-row pass
    const int srcch = (tid & 7) ^ ((tid >> 3) & 7); // swizzled source chunk
    const int ldst = (tid & 192) * 8;               // wave-uniform LDS u16 base

    const f32x4 fzero = {0.f, 0.f, 0.f, 0.f};
    f32x4 acc[MI][NI];
#pragma unroll
    for (int i = 0; i < MI; i++)
#pragma unroll
        for (int j = 0; j < NI; j++) acc[i][j] = fzero;

    const int nkt = K >> 6;

#define STAGE(buf, kt)                                                          \
    {                                                                           \
        const int k0s = (kt) << 6;                                              \
        _Pragma("unroll")                                                       \
        for (int i = 0; i < MI; i++) {                                          \
            const int r = i * 32 + f_r;                                         \
            gll16(&A[(size_t)(m0 + r) * K + k0s + srcch * 8],                   \
                  &Al[buf][i * 2048 + ldst]);                                   \
        }                                                                       \
        _Pragma("unroll")                                                       \
        for (int i = 0; i < NI; i++) {                                          \
            const int r = i * 32 + f_r;                                         \
            gll16(&Bt[(size_t)(n0 + r) * K + k0s + srcch * 8],                  \
                  &Bl[buf][i * 2048 + ldst]);                                   \
        }                                                                       \
    }

    STAGE(0, 0);
    asm volatile("s_waitcnt vmcnt(0)" ::: "memory");
    __syncthreads();
    int cur = 0;
    for (int kt = 0; kt < nkt; kt++) {
        if (kt + 1 < nkt) STAGE(cur ^ 1, kt + 1);
#pragma unroll
        for (int ks = 0; ks < 2; ks++) {
            bf16x8 af[MI], bfv[NI];
#pragma unroll
            for (int mi = 0; mi < MI; mi++) {
                const int rowA = wr * (MI * 16) + mi * 16 + lr;
                af[mi] = *(const bf16x8*)&Al[cur][rowA * 64 +
                                                  (((ks * 4 + lq) ^ (rowA & 7)) << 3)];
            }
#pragma unroll
            for (int ni = 0; ni < NI; ni++) {
                const int rowB = wc * (NI * 16) + ni * 16 + lr;
                bfv[ni] = *(const bf16x8*)&Bl[cur][rowB * 64 +
                                                   (((ks * 4 + lq) ^ (rowB & 7)) << 3)];
            }
#pragma unroll
            for (int mi = 0; mi < MI; mi++)
#pragma unroll
                for (int ni = 0; ni < NI; ni++)
                    acc[mi][ni] = MFMA(af[mi], bfv[ni], acc[mi][ni]);
        }
        asm volatile("s_waitcnt vmcnt(0)" ::: "memory");
        __syncthreads();
        cur ^= 1;
    }
#undef STAGE

#pragma unroll
    for (int mi = 0; mi < MI; mi++)
#pragma unroll
        for (int ni = 0; ni < NI; ni++)
#pragma unroll
            for (int j = 0; j < 4; j++) {
                const int row = m0 + wr * (MI * 16) + mi * 16 + lq * 4 + j;
                const int col = n0 + wc * (NI * 16) + ni * 16 + lr;
                const float v = acc[mi][ni][j];
                if (EPI) {
                    ((float*)Cp)[(size_t)row * N + col] =
                        v + bias[col] + resid[(size_t)row * N + col];
                } else if (TRANSC) {
                    ((u16*)Cp)[((size_t)(col >> 11) * 1280 + row) * 2048 +
                               (col & 2047)] = f2bf(v);
                } else {
                    ((u16*)Cp)[(size_t)row * N + col] = f2bf(v);
                }
            }
}

// ---------------------------------------------------------------------------
// Flash attention — R17-proven: TWO barriers per tile, double-buffered K/V.
// Grid 512 (h = id&7 -> XCD-local K/V; bz=(id>>3)&1; qt=id>>4, 32 q-rows).
// Block 256 thr = 4 waves = 2 qg x 2 kc; 32-key tiles, 64 tiles.
// Disjoint output slabs, no end merge; l via ones-MFMA. No max-tracking.
// Plain launch_bounds (min-waves arg spills: R3/R5/R10; >8 staging uint4
// spills: R9/R13/R18). 50.5 KB LDS, 68 VGPR clean.
// ---------------------------------------------------------------------------
__global__ __launch_bounds__(256) void attn_kernel(
    const u16* __restrict__ qb, const u16* __restrict__ kb,
    const u16* __restrict__ vtb, const int* __restrict__ seg,
    u16* __restrict__ ao) {
    __shared__ __align__(16) u16 arena[25856];
    // buffer b at b*11776: K [32][168] (5376 u16) + Vt [160][40] (6400 u16)
    const int VT = 5376;
    const int PT = 23552;  // P  2 x [16][40] u16 (1280)
    const int SG = 24832;  // seg u8[8][256]      (1024 u16)
    u8* segl8 = (u8*)&arena[SG];

    const int tid = threadIdx.x;
    const int lane = tid & 63, w = tid >> 6;
    const int qg = w >> 1, kc = w & 1;
    const int lr = lane & 15, lq = lane >> 4;
    const int id = blockIdx.x;
    const int h = id & 7, bz = (id >> 3) & 1, qt = id >> 4;  // qt 0..31

    // seg rows qt*8..+8 as bytes (2048 ints, 8 per thread)
#pragma unroll
    for (int i = 0; i < 2; i++) {
        const int4 v =
            *(const int4*)&seg[(size_t)(bz * 256 + qt * 8) * 256 + tid * 8 + i * 4];
        segl8[tid * 8 + i * 4 + 0] = (u8)v.x;
        segl8[tid * 8 + i * 4 + 1] = (u8)v.y;
        segl8[tid * 8 + i * 4 + 2] = (u8)v.z;
        segl8[tid * 8 + i * 4 + 3] = (u8)v.w;
    }

    // Q fragments (A-operand; wave-pair qg owns q-rows qt*32+qg*16+[0,16))
    bf16x8 qf[5];
    {
        const size_t qrow =
            (size_t)(bz * 1024 + qt * 32 + qg * 16 + lr) * 1280 + h * 160;
#pragma unroll
        for (int ks = 0; ks < 5; ks++)
            qf[ks] = *(const bf16x8*)&qb[qrow + ks * 32 + lq * 8];
    }

    // staging geometry: K 640 chunks (row=n/20, c8=n%20), V 640 (d=n>>2, c=n&3)
    const int nk0 = tid, nk1 = tid + 256;
    const int nv0 = tid, nv1 = tid + 256;
    const bool exK = (tid < 128);
    const int ne = exK ? (512 + tid) : (384 + tid);
    const int gok0 = (nk0 / 20) * 1280 + (nk0 % 20) * 8;
    const int lok0 = (nk0 / 20) * 168 + (nk0 % 20) * 8;
    const int gok1 = (nk1 / 20) * 1280 + (nk1 % 20) * 8;
    const int lok1 = (nk1 / 20) * 168 + (nk1 % 20) * 8;
    const int gov0 = (nv0 >> 2) * 2048 + (nv0 & 3) * 8;
    const int lov0 = VT + (nv0 >> 2) * 40 + (nv0 & 3) * 8;
    const int gov1 = (nv1 >> 2) * 2048 + (nv1 & 3) * 8;
    const int lov1 = VT + (nv1 >> 2) * 40 + (nv1 & 3) * 8;
    const int goe = exK ? ((ne / 20) * 1280 + (ne % 20) * 8)
                        : ((ne >> 2) * 2048 + (ne & 3) * 8);
    const int loe = exK ? ((ne / 20) * 168 + (ne % 20) * 8)
                        : (VT + (ne >> 2) * 40 + (ne & 3) * 8);

    const u16* kP = kb + (size_t)(bz * 2048) * 1280 + h * 160;    // + kt*40960
    const u16* vP = vtb + (size_t)(bz * 1280 + h * 160) * 2048;   // + kt*32

    const f32x4 fzero = {0.f, 0.f, 0.f, 0.f};
    f32x4 oacc[5];
#pragma unroll
    for (int d = 0; d < 5; d++) oacc[d] = fzero;
    f32x4 oaccL = fzero;
    const float sc2 = 0.11405508f;  // (1/sqrt(160)) * log2(e)
    bf16x8 ones8;
#pragma unroll
    for (int e = 0; e < 8; e++) {
        const u16 one = 0x3F80;
        ones8[e] = *(const __bf16*)&one;
    }
    u16* ptq = &arena[PT + qg * 640];  // shared P tile of this q-group

    // prologue: tile 0 -> regs -> buf0; barrier covers buf0 + segl
    uint4 rk0 = *(const uint4*)&kP[gok0];
    uint4 rk1 = *(const uint4*)&kP[gok1];
    uint4 rv0 = *(const uint4*)&vP[gov0];
    uint4 rv1 = *(const uint4*)&vP[gov1];
    uint4 re  = exK ? *(const uint4*)&kP[goe] : *(const uint4*)&vP[goe];
    *(uint4*)&arena[lok0] = rk0;
    *(uint4*)&arena[lok1] = rk1;
    *(uint4*)&arena[lov0] = rv0;
    *(uint4*)&arena[lov1] = rv1;
    *(uint4*)&arena[loe] = re;
    kP += 40960;
    vP += 32;
    __syncthreads();

    int cb = 0;  // current buffer base (u16 offset)
    for (int kt = 0; kt < 64; kt++) {
        // issue next-tile loads: one full QK+exp+PV phase to complete
        if (kt + 1 < 64) {
            rk0 = *(const uint4*)&kP[gok0];
            rk1 = *(const uint4*)&kP[gok1];
            rv0 = *(const uint4*)&vP[gov0];
            rv1 = *(const uint4*)&vP[gov1];
            re  = exK ? *(const uint4*)&kP[goe] : *(const uint4*)&vP[goe];
            kP += 40960;
            vP += 32;
        }

        // --- QK^T: 16 q-rows x 16 keys (kc half), 2 interleaved chains ---
        const u16* kbase = &arena[cb + (kc * 16 + lr) * 168 + lq * 8];
        f32x4 sA = fzero, sB = fzero;
        sA = MFMA(qf[0], *(const bf16x8*)&kbase[0],   sA);
        sB = MFMA(qf[1], *(const bf16x8*)&kbase[32],  sB);
        sA = MFMA(qf[2], *(const bf16x8*)&kbase[64],  sA);
        sB = MFMA(qf[3], *(const bf16x8*)&kbase[96],  sB);
        sA = MFMA(qf[4], *(const bf16x8*)&kbase[128], sA);

        // scale + seg mask (keys >= 1024 iff kt >= 32; byte uniform over j)
        float msk = 0.f;
        if (kt >= 32) {
            const int sg = (kt - 32) * 8 + kc * 4 + (lr >> 2);
            msk = segl8[(qg * 4 + lq) * 256 + sg] ? 0.f : -1e30f;
        }
        // p = exp2(s*sc2 + msk); P -> shared q-group LDS tile at kc*16 offset
#pragma unroll
        for (int j = 0; j < 4; j++) {
            const float e = EXP2(fmaf(sA[j] + sB[j], sc2, msk));
            *(__bf16*)&ptq[(lq * 4 + j) * 40 + kc * 16 + lr] = (__bf16)e;
        }
        __syncthreads();  // barrier 1: P visible across the kc pair

        // --- PV at K=32 over ALL 32 keys; this wave owns d-cols kc*80..+80 ---
        const bf16x8 pa = *(const bf16x8*)&ptq[lr * 40 + lq * 8];
        oaccL = MFMA(pa, ones8, oaccL);  // row-sum l (identical in both waves)
#pragma unroll
        for (int nt2 = 0; nt2 < 5; nt2++) {
            const bf16x8 bv = *(const bf16x8*)
                &arena[cb + VT + (kc * 80 + nt2 * 16 + lr) * 40 + lq * 8];
            oacc[nt2] = MFMA(pa, bv, oacc[nt2]);
        }

        // --- stage next tile into the OTHER buffer (vmcnt waits here) ---
        if (kt + 1 < 64) {
            const int nb = cb ^ 11776;
            *(uint4*)&arena[nb + lok0] = rk0;
            *(uint4*)&arena[nb + lok1] = rk1;
            *(uint4*)&arena[nb + lov0] = rv0;
            *(uint4*)&arena[nb + lov1] = rv1;
            *(uint4*)&arena[nb + loe] = re;
        }
        __syncthreads();  // barrier 2: staging visible; P/V reads done
        cb ^= 11776;
    }

    // ---- normalize and write own disjoint [16q x 80d] slab ----
    float inv[4];
#pragma unroll
    for (int j = 0; j < 4; j++) inv[j] = 1.f / oaccL[j];
#pragma unroll
    for (int nt2 = 0; nt2 < 5; nt2++)
#pragma unroll
        for (int j = 0; j < 4; j++) {
            const int row = qt * 32 + qg * 16 + lq * 4 + j;
            const int col = h * 160 + kc * 80 + nt2 * 16 + lr;
            *(__bf16*)&ao[(size_t)(bz * 1024 + row) * 1280 + col] =
                (__bf16)(oacc[nt2][j] * inv[j]);
        }
}

// ---------------------------------------------------------------------------
extern "C" void kernel_launch(void* const* d_in, const int* in_sizes, int n_in,
                              void* d_out, int out_size, void* d_ws, size_t ws_size,
                              hipStream_t stream) {
    const float* hs  = (const float*)d_in[0];
    const float* ehs = (const float*)d_in[1];
    const int*   seg = (const int*)d_in[2];
    const float* Wq  = (const float*)d_in[3];
    const float* Wk  = (const float*)d_in[4];
    const float* Wv  = (const float*)d_in[5];
    const float* Wo  = (const float*)d_in[6];
    const float* bo  = (const float*)d_in[7];
    float* out = (float*)d_out;

    u16* base  = (u16*)d_ws;
    u16* WoT   = base;                  // 1,638,400
    u16* qbuf  = WoT + 1638400;         // 2,621,440
    u16* kbuf  = qbuf + 2621440;        // 5,242,880
    u16* vtbuf = kbuf + 5242880;        // 5,242,880
    u16* hbuf  = vtbuf + 5242880;       // 2,621,440 (= aobuf after attn)
    u16* ebuf  = hbuf + 2621440;        // 5,242,880
    u16* WqT   = ebuf + 5242880;        // 1,638,400
    u16* WkT   = WqT + 1638400;         // 1,638,400
    u16* WvT   = WkT + 1638400;         // 1,638,400
    u16* aobuf = hbuf;

    prep_kernel<<<10240, 256, 0, stream>>>(hs, hbuf, ehs, ebuf, Wq, Wk, Wv, Wo,
                                           WqT, WkT, WvT, WoT);

    gemm2_kernel<2, 2, false, false><<<dim3(20, 32), 256, 0, stream>>>(
        hbuf, WqT, qbuf, nullptr, nullptr, 2048, 1280, 1280);
    gemm2_kernel<2, 2, false, false><<<dim3(20, 64), 256, 0, stream>>>(
        ebuf, WkT, kbuf, nullptr, nullptr, 4096, 1280, 1280);
    gemm2_kernel<2, 2, true, false><<<dim3(64, 20), 256, 0, stream>>>(
        WvT, ebuf, vtbuf, nullptr, nullptr, 1280, 4096, 1280);

    attn_kernel<<<512, 256, 0, stream>>>(qbuf, kbuf, vtbuf, seg, aobuf);

    gemm2_kernel<2, 2, false, true><<<dim3(20, 32), 256, 0, stream>>>(
        aobuf, WoT, out, bo, hs, 2048, 1280, 1280);
}

// Round 21
// 157.967 us; speedup vs baseline: 1.0580x; 1.0580x over previous
//
#include <hip/hip_runtime.h>

typedef unsigned short u16;
typedef unsigned int   u32;
typedef unsigned char  u8;

using bf16x8 = __attribute__((ext_vector_type(8))) __bf16;
using f32x4  = __attribute__((ext_vector_type(4))) float;

__device__ __forceinline__ u16 f2bf(float f) {
    u32 u = __float_as_uint(f);
    return (u16)((u + 0x7FFFu + ((u >> 16) & 1u)) >> 16);
}

#define MFMA(a, b, c) __builtin_amdgcn_mfma_f32_16x16x32_bf16((a), (b), (c), 0, 0, 0)
#define EXP2(x) __builtin_amdgcn_exp2f(x)

// async global->LDS 16B: per-lane global source, wave-uniform LDS base + lane*16
__device__ __forceinline__ void gll16(const u16* g, u16* l) {
    __builtin_amdgcn_global_load_lds(
        (const __attribute__((address_space(1))) void*)g,
        (__attribute__((address_space(3))) void*)l, 16, 0, 0);
}

// ---------------------------------------------------------------------------
// MERGED prep: fp32->bf16 conversion of hs/ehs (blocks 0..3839) + 4 weight
// transposes Wt[n][k] = bf16(W[k][n]) (blocks 3840..10239). (R19-proven.)
// ---------------------------------------------------------------------------
__global__ __launch_bounds__(256) void prep_kernel(
    const float* __restrict__ hs, u16* __restrict__ hbuf,
    const float* __restrict__ ehs, u16* __restrict__ ebuf,
    const float* __restrict__ W0, const float* __restrict__ W1,
    const float* __restrict__ W2, const float* __restrict__ W3,
    u16* __restrict__ T0, u16* __restrict__ T1,
    u16* __restrict__ T2, u16* __restrict__ T3) {
    const int bid = blockIdx.x;
    const int tid = threadIdx.x;
    if (bid < 3840) {
        const float* in = (bid < 1280) ? hs : ehs;
        u16* out = (bid < 1280) ? hbuf : ebuf;
        const int i = ((bid < 1280) ? bid : bid - 1280) * 256 + tid;
        const float4 a = ((const float4*)in)[i * 2];
        const float4 b = ((const float4*)in)[i * 2 + 1];
        union { uint4 u; u16 s[8]; } cv;
        cv.s[0] = f2bf(a.x); cv.s[1] = f2bf(a.y);
        cv.s[2] = f2bf(a.z); cv.s[3] = f2bf(a.w);
        cv.s[4] = f2bf(b.x); cv.s[5] = f2bf(b.y);
        cv.s[6] = f2bf(b.z); cv.s[7] = f2bf(b.w);
        ((uint4*)out)[i] = cv.u;
    } else {
        const int N = 1280;
        const int t = bid - 3840;        // 0..6399
        const int z = t / 1600;
        const int r = t % 1600;
        const float* W = (z == 0) ? W0 : (z == 1) ? W1 : (z == 2) ? W2 : W3;
        u16* T = (z == 0) ? T0 : (z == 1) ? T1 : (z == 2) ? T2 : T3;
        __shared__ float tt[32][33];
        const int bx = (r % 40) * 32, by = (r / 40) * 32;
        const int x = tid & 31, ty = tid >> 5;
#pragma unroll
        for (int j = 0; j < 4; j++) {
            const int y = ty + j * 8;
            tt[y][x] = W[(size_t)(by + y) * N + (bx + x)];
        }
        __syncthreads();
#pragma unroll
        for (int j = 0; j < 4; j++) {
            const int y = ty + j * 8;
            T[(size_t)(bx + y) * N + (by + x)] = f2bf(tt[x][y]);
        }
    }
}

// ---------------------------------------------------------------------------
// C[M,N] = A[M,K] @ Bt[N,K]^T, bf16 in. m97-structure: global_load_lds into
// linear LDS, pre-swizzled source chunk (^= row&7), swizzled ds_read_b128,
// double-buffered, one vmcnt(0)+barrier per K-tile. BM=MI*32, BN=128.
// (R14/R17/R19-proven optimum; 3-buffer, merged-launch, 64x64-tile variants
// all regressed.)
// ---------------------------------------------------------------------------
template <int MI, bool TRANSC, bool EPI>
__global__ __launch_bounds__(256) void gemm2_kernel(
    const u16* __restrict__ A, const u16* __restrict__ Bt, void* __restrict__ Cp,
    const float* __restrict__ bias, const float* __restrict__ resid,
    const int M, const int N, const int K) {
    __shared__ __align__(16) u16 Al[2][MI * 32 * 64];
    __shared__ __align__(16) u16 Bl[2][128 * 64];
    const int tid = threadIdx.x;
    const int lane = tid & 63, w = tid >> 6;
    const int wr = w >> 1, wc = w & 1;
    const int lr = lane & 15, lq = lane >> 4;
    const int m0 = blockIdx.y * (MI * 32), n0 = blockIdx.x * 128;

    const int f_r = tid >> 3;                       // row within 32-row pass
    const int srcch = (tid & 7) ^ ((tid >> 3) & 7); // swizzled source chunk
    const int ldst = (tid & 192) * 8;               // wave-uniform LDS u16 base

    const f32x4 fzero = {0.f, 0.f, 0.f, 0.f};
    f32x4 acc[MI][4];
#pragma unroll
    for (int i = 0; i < MI; i++)
#pragma unroll
        for (int j = 0; j < 4; j++) acc[i][j] = fzero;

    const int nkt = K >> 6;

#define STAGE(buf, kt)                                                          \
    {                                                                           \
        const int k0s = (kt) << 6;                                              \
        _Pragma("unroll")                                                       \
        for (int i = 0; i < MI; i++) {                                          \
            const int r = i * 32 + f_r;                                         \
            gll16(&A[(size_t)(m0 + r) * K + k0s + srcch * 8],                   \
                  &Al[buf][i * 2048 + ldst]);                                   \
        }                                                                       \
        _Pragma("unroll")                                                       \
        for (int i = 0; i < 4; i++) {                                           \
            const int r = i * 32 + f_r;                                         \
            gll16(&Bt[(size_t)(n0 + r) * K + k0s + srcch * 8],                  \
                  &Bl[buf][i * 2048 + ldst]);                                   \
        }                                                                       \
    }

    STAGE(0, 0);
    asm volatile("s_waitcnt vmcnt(0)" ::: "memory");
    __syncthreads();
    int cur = 0;
    for (int kt = 0; kt < nkt; kt++) {
        if (kt + 1 < nkt) STAGE(cur ^ 1, kt + 1);
#pragma unroll
        for (int ks = 0; ks < 2; ks++) {
            bf16x8 af[MI], bfv[4];
#pragma unroll
            for (int mi = 0; mi < MI; mi++) {
                const int rowA = wr * (MI * 16) + mi * 16 + lr;
                af[mi] = *(const bf16x8*)&Al[cur][rowA * 64 +
                                                  (((ks * 4 + lq) ^ (rowA & 7)) << 3)];
            }
#pragma unroll
            for (int ni = 0; ni < 4; ni++) {
                const int rowB = wc * 64 + ni * 16 + lr;
                bfv[ni] = *(const bf16x8*)&Bl[cur][rowB * 64 +
                                                   (((ks * 4 + lq) ^ (rowB & 7)) << 3)];
            }
#pragma unroll
            for (int mi = 0; mi < MI; mi++)
#pragma unroll
                for (int ni = 0; ni < 4; ni++)
                    acc[mi][ni] = MFMA(af[mi], bfv[ni], acc[mi][ni]);
        }
        asm volatile("s_waitcnt vmcnt(0)" ::: "memory");
        __syncthreads();
        cur ^= 1;
    }
#undef STAGE

#pragma unroll
    for (int mi = 0; mi < MI; mi++)
#pragma unroll
        for (int ni = 0; ni < 4; ni++)
#pragma unroll
            for (int j = 0; j < 4; j++) {
                const int row = m0 + wr * (MI * 16) + mi * 16 + lq * 4 + j;
                const int col = n0 + wc * 64 + ni * 16 + lr;
                const float v = acc[mi][ni][j];
                if (EPI) {
                    ((float*)Cp)[(size_t)row * N + col] =
                        v + bias[col] + resid[(size_t)row * N + col];
                } else if (TRANSC) {
                    ((u16*)Cp)[((size_t)(col >> 11) * 1280 + row) * 2048 +
                               (col & 2047)] = f2bf(v);
                } else {
                    ((u16*)Cp)[(size_t)row * N + col] = f2bf(v);
                }
            }
}

// ---------------------------------------------------------------------------
// Flash attention — R17-proven: TWO barriers per tile, double-buffered K/V.
// Grid 512 (h = id&7 -> XCD-local K/V; bz=(id>>3)&1; qt=id>>4, 32 q-rows).
// Block 256 thr = 4 waves = 2 qg x 2 kc; 32-key tiles, 64 tiles.
//   issue t+1 global loads -> QK from buf[b] (kc-split, 5 MFMA) -> exp -> P
//   -> barrier 1 (P visible) -> PV from buf[b]+P (K=32 full rate, wave owns
//   d-cols kc*80..+80) -> stage regs into buf[b^1] -> barrier 2 -> flip.
// Disjoint output slabs, no end merge; l via ones-MFMA. No max-tracking
// (scores bounded; masked -> exp2(-1e30)=0). Plain launch_bounds (min-waves
// arg spills: R3/R5/R10; >8 staging uint4 spills: R9/R13/R18).
// 50.5 KB LDS (2 blk/CU — grid-limited), 68 VGPR clean.
// ---------------------------------------------------------------------------
__global__ __launch_bounds__(256) void attn_kernel(
    const u16* __restrict__ qb, const u16* __restrict__ kb,
    const u16* __restrict__ vtb, const int* __restrict__ seg,
    u16* __restrict__ ao) {
    __shared__ __align__(16) u16 arena[25856];
    // buffer b at b*11776: K [32][168] (5376 u16) + Vt [160][40] (6400 u16)
    const int VT = 5376;
    const int PT = 23552;  // P  2 x [16][40] u16 (1280)
    const int SG = 24832;  // seg u8[8][256]      (1024 u16)
    u8* segl8 = (u8*)&arena[SG];

    const int tid = threadIdx.x;
    const int lane = tid & 63, w = tid >> 6;
    const int qg = w >> 1, kc = w & 1;
    const int lr = lane & 15, lq = lane >> 4;
    const int id = blockIdx.x;
    const int h = id & 7, bz = (id >> 3) & 1, qt = id >> 4;  // qt 0..31

    // seg rows qt*8..+8 as bytes (2048 ints, 8 per thread)
#pragma unroll
    for (int i = 0; i < 2; i++) {
        const int4 v =
            *(const int4*)&seg[(size_t)(bz * 256 + qt * 8) * 256 + tid * 8 + i * 4];
        segl8[tid * 8 + i * 4 + 0] = (u8)v.x;
        segl8[tid * 8 + i * 4 + 1] = (u8)v.y;
        segl8[tid * 8 + i * 4 + 2] = (u8)v.z;
        segl8[tid * 8 + i * 4 + 3] = (u8)v.w;
    }

    // Q fragments (A-operand; wave-pair qg owns q-rows qt*32+qg*16+[0,16))
    bf16x8 qf[5];
    {
        const size_t qrow =
            (size_t)(bz * 1024 + qt * 32 + qg * 16 + lr) * 1280 + h * 160;
#pragma unroll
        for (int ks = 0; ks < 5; ks++)
            qf[ks] = *(const bf16x8*)&qb[qrow + ks * 32 + lq * 8];
    }

    // staging geometry: K 640 chunks (row=n/20, c8=n%20), V 640 (d=n>>2, c=n&3)
    const int nk0 = tid, nk1 = tid + 256;
    const int nv0 = tid, nv1 = tid + 256;
    const bool exK = (tid < 128);
    const int ne = exK ? (512 + tid) : (384 + tid);
    const int gok0 = (nk0 / 20) * 1280 + (nk0 % 20) * 8;
    const int lok0 = (nk0 / 20) * 168 + (nk0 % 20) * 8;
    const int gok1 = (nk1 / 20) * 1280 + (nk1 % 20) * 8;
    const int lok1 = (nk1 / 20) * 168 + (nk1 % 20) * 8;
    const int gov0 = (nv0 >> 2) * 2048 + (nv0 & 3) * 8;
    const int lov0 = VT + (nv0 >> 2) * 40 + (nv0 & 3) * 8;
    const int gov1 = (nv1 >> 2) * 2048 + (nv1 & 3) * 8;
    const int lov1 = VT + (nv1 >> 2) * 40 + (nv1 & 3) * 8;
    const int goe = exK ? ((ne / 20) * 1280 + (ne % 20) * 8)
                        : ((ne >> 2) * 2048 + (ne & 3) * 8);
    const int loe = exK ? ((ne / 20) * 168 + (ne % 20) * 8)
                        : (VT + (ne >> 2) * 40 + (ne & 3) * 8);

    const u16* kP = kb + (size_t)(bz * 2048) * 1280 + h * 160;    // + kt*40960
    const u16* vP = vtb + (size_t)(bz * 1280 + h * 160) * 2048;   // + kt*32

    const f32x4 fzero = {0.f, 0.f, 0.f, 0.f};
    f32x4 oacc[5];
#pragma unroll
    for (int d = 0; d < 5; d++) oacc[d] = fzero;
    f32x4 oaccL = fzero;
    const float sc2 = 0.11405508f;  // (1/sqrt(160)) * log2(e)
    bf16x8 ones8;
#pragma unroll
    for (int e = 0; e < 8; e++) {
        const u16 one = 0x3F80;
        ones8[e] = *(const __bf16*)&one;
    }
    u16* ptq = &arena[PT + qg * 640];  // shared P tile of this q-group

    // prologue: tile 0 -> regs -> buf0; barrier covers buf0 + segl
    uint4 rk0 = *(const uint4*)&kP[gok0];
    uint4 rk1 = *(const uint4*)&kP[gok1];
    uint4 rv0 = *(const uint4*)&vP[gov0];
    uint4 rv1 = *(const uint4*)&vP[gov1];
    uint4 re  = exK ? *(const uint4*)&kP[goe] : *(const uint4*)&vP[goe];
    *(uint4*)&arena[lok0] = rk0;
    *(uint4*)&arena[lok1] = rk1;
    *(uint4*)&arena[lov0] = rv0;
    *(uint4*)&arena[lov1] = rv1;
    *(uint4*)&arena[loe] = re;
    kP += 40960;
    vP += 32;
    __syncthreads();

    int cb = 0;  // current buffer base (u16 offset)
    for (int kt = 0; kt < 64; kt++) {
        // issue next-tile loads: one full QK+exp+PV phase to complete
        if (kt + 1 < 64) {
            rk0 = *(const uint4*)&kP[gok0];
            rk1 = *(const uint4*)&kP[gok1];
            rv0 = *(const uint4*)&vP[gov0];
            rv1 = *(const uint4*)&vP[gov1];
            re  = exK ? *(const uint4*)&kP[goe] : *(const uint4*)&vP[goe];
            kP += 40960;
            vP += 32;
        }

        // --- QK^T: 16 q-rows x 16 keys (kc half), 2 interleaved chains ---
        const u16* kbase = &arena[cb + (kc * 16 + lr) * 168 + lq * 8];
        f32x4 sA = fzero, sB = fzero;
        sA = MFMA(qf[0], *(const bf16x8*)&kbase[0],   sA);
        sB = MFMA(qf[1], *(const bf16x8*)&kbase[32],  sB);
        sA = MFMA(qf[2], *(const bf16x8*)&kbase[64],  sA);
        sB = MFMA(qf[3], *(const bf16x8*)&kbase[96],  sB);
        sA = MFMA(qf[4], *(const bf16x8*)&kbase[128], sA);

        // scale + seg mask (keys >= 1024 iff kt >= 32; byte uniform over j)
        float msk = 0.f;
        if (kt >= 32) {
            const int sg = (kt - 32) * 8 + kc * 4 + (lr >> 2);
            msk = segl8[(qg * 4 + lq) * 256 + sg] ? 0.f : -1e30f;
        }
        // p = exp2(s*sc2 + msk); P -> shared q-group LDS tile at kc*16 offset
#pragma unroll
        for (int j = 0; j < 4; j++) {
            const float e = EXP2(fmaf(sA[j] + sB[j], sc2, msk));
            *(__bf16*)&ptq[(lq * 4 + j) * 40 + kc * 16 + lr] = (__bf16)e;
        }
        __syncthreads();  // barrier 1: P visible across the kc pair

        // --- PV at K=32 over ALL 32 keys; this wave owns d-cols kc*80..+80 ---
        const bf16x8 pa = *(const bf16x8*)&ptq[lr * 40 + lq * 8];
        oaccL = MFMA(pa, ones8, oaccL);  // row-sum l (identical in both waves)
#pragma unroll
        for (int nt2 = 0; nt2 < 5; nt2++) {
            const bf16x8 bv = *(const bf16x8*)
                &arena[cb + VT + (kc * 80 + nt2 * 16 + lr) * 40 + lq * 8];
            oacc[nt2] = MFMA(pa, bv, oacc[nt2]);
        }

        // --- stage next tile into the OTHER buffer (vmcnt waits here) ---
        if (kt + 1 < 64) {
            const int nb = cb ^ 11776;
            *(uint4*)&arena[nb + lok0] = rk0;
            *(uint4*)&arena[nb + lok1] = rk1;
            *(uint4*)&arena[nb + lov0] = rv0;
            *(uint4*)&arena[nb + lov1] = rv1;
            *(uint4*)&arena[nb + loe] = re;
        }
        __syncthreads();  // barrier 2: staging visible; P/V reads done
        cb ^= 11776;
    }

    // ---- normalize and write own disjoint [16q x 80d] slab ----
    float inv[4];
#pragma unroll
    for (int j = 0; j < 4; j++) inv[j] = 1.f / oaccL[j];
#pragma unroll
    for (int nt2 = 0; nt2 < 5; nt2++)
#pragma unroll
        for (int j = 0; j < 4; j++) {
            const int row = qt * 32 + qg * 16 + lq * 4 + j;
            const int col = h * 160 + kc * 80 + nt2 * 16 + lr;
            *(__bf16*)&ao[(size_t)(bz * 1024 + row) * 1280 + col] =
                (__bf16)(oacc[nt2][j] * inv[j]);
        }
}

// ---------------------------------------------------------------------------
extern "C" void kernel_launch(void* const* d_in, const int* in_sizes, int n_in,
                              void* d_out, int out_size, void* d_ws, size_t ws_size,
                              hipStream_t stream) {
    const float* hs  = (const float*)d_in[0];
    const float* ehs = (const float*)d_in[1];
    const int*   seg = (const int*)d_in[2];
    const float* Wq  = (const float*)d_in[3];
    const float* Wk  = (const float*)d_in[4];
    const float* Wv  = (const float*)d_in[5];
    const float* Wo  = (const float*)d_in[6];
    const float* bo  = (const float*)d_in[7];
    float* out = (float*)d_out;

    u16* base  = (u16*)d_ws;
    u16* WoT   = base;                  // 1,638,400
    u16* qbuf  = WoT + 1638400;         // 2,621,440
    u16* kbuf  = qbuf + 2621440;        // 5,242,880
    u16* vtbuf = kbuf + 5242880;        // 5,242,880
    u16* hbuf  = vtbuf + 5242880;       // 2,621,440 (= aobuf after attn)
    u16* ebuf  = hbuf + 2621440;        // 5,242,880
    u16* WqT   = ebuf + 5242880;        // 1,638,400
    u16* WkT   = WqT + 1638400;         // 1,638,400
    u16* WvT   = WkT + 1638400;         // 1,638,400
    u16* aobuf = hbuf;

    prep_kernel<<<10240, 256, 0, stream>>>(hs, hbuf, ehs, ebuf, Wq, Wk, Wv, Wo,
                                           WqT, WkT, WvT, WoT);

    gemm2_kernel<1, false, false><<<dim3(10, 64), 256, 0, stream>>>(
        hbuf, WqT, qbuf, nullptr, nullptr, 2048, 1280, 1280);
    gemm2_kernel<2, false, false><<<dim3(10, 64), 256, 0, stream>>>(
        ebuf, WkT, kbuf, nullptr, nullptr, 4096, 1280, 1280);
    gemm2_kernel<2, true, false><<<dim3(32, 20), 256, 0, stream>>>(
        WvT, ebuf, vtbuf, nullptr, nullptr, 1280, 4096, 1280);

    attn_kernel<<<512, 256, 0, stream>>>(qbuf, kbuf, vtbuf, seg, aobuf);

    gemm2_kernel<1, false, true><<<dim3(10, 64), 256, 0, stream>>>(
        aobuf, WoT, out, bo, hs, 2048, 1280, 1280);
}